// Round 22
// baseline (232.821 us; speedup 1.0000x reference)
//
#include <hip/hip_runtime.h>
#include <hip/hip_bf16.h>
#include <math.h>

// ---------------------------------------------------------------------------
// GPT block on MI355X (gfx950). bf16 MFMA compute, fp32 accumulate.
// Workspace layout (MB = 1<<20), total 72 MB:
//   [ 0, 6)  WtQKV  bf16 [3072][1024]  -- dead after QKV; attn S/m partials,
//                                         then proj partial0 (bf16 8MB)
//   [ 6, 8)  WtO    bf16 [1024][1024]
//   [ 8,16)  Wtfc   bf16 [4096][1024]
//   [16,24)  Wtproj bf16 [1024][4096]
//   [24,32)  zn / ctx   bf16           -- dead after O-proj; proj partial1
//   [32,40)  Q / h      bf16
//   [40,48)  K          bf16
//   [48,56)  Vt         bf16 [32][64][2048]  (V transposed, kv-permuted)
//   [56,72)  attn O-partials bf16 [1024][128][64]
//   [40,72)  ffn1       bf16 [4096][4096]  (after attn+combine)
// attn: SPLIT-KV (r18 retry). BUG FIX vs r18: Mp is indexed by the softmax
// row lr (the row whose max m_s actually is, per the mfma(K,Q) D-layout),
// not the D-layout row 4g+r. Sp/O stay D-layout-indexed.
// QKV: 2-phase 128x96, LDS-transposed V epilogue. fc: 8-phase 256^2.
// proj: split-K=2 bf16 partials + reduce.
// ---------------------------------------------------------------------------

typedef __bf16 bf16x8 __attribute__((ext_vector_type(8)));
typedef float  f32x4  __attribute__((ext_vector_type(4)));

#define MFMA_16x16x32_BF16(A, B, C) __builtin_amdgcn_mfma_f32_16x16x32_bf16((A), (B), (C), 0, 0, 0)

#define GLDS16(g, l) __builtin_amdgcn_global_load_lds( \
    (const __attribute__((address_space(1))) void*)(g), \
    (__attribute__((address_space(3))) void*)(l), 16, 0, 0)

__device__ __forceinline__ float fmax3(float a, float b, float c) {
    return fmaxf(fmaxf(a, b), c);   // clang fuses to v_max3_f32
}

// ---------------- fused head: 6 weight transposes + rmsnorm(z,g1) -----------
__global__ __launch_bounds__(256) void fused_head_kernel(
    const float* __restrict__ W_Q, const float* __restrict__ W_K,
    const float* __restrict__ W_V, const float* __restrict__ W_O,
    const float* __restrict__ W_fc, const float* __restrict__ W_proj,
    __bf16* __restrict__ WtQKV, __bf16* __restrict__ WtO,
    __bf16* __restrict__ Wtfc, __bf16* __restrict__ Wtproj,
    const float* __restrict__ z, const float* __restrict__ g1,
    __bf16* __restrict__ zn)
{
    const int id = blockIdx.x;
    if (id >= 12288) {
        const int row = id - 12288, t = threadIdx.x;
        const float4 v = ((const float4*)(z + (size_t)row * 1024))[t];
        float ss = v.x * v.x + v.y * v.y + v.z * v.z + v.w * v.w;
#pragma unroll
        for (int m = 1; m < 64; m <<= 1) ss += __shfl_xor(ss, m);
        __shared__ float red[4];
        const int wid = t >> 6, lane = t & 63;
        if (lane == 0) red[wid] = ss;
        __syncthreads();
        const float tot = red[0] + red[1] + red[2] + red[3];
        const float inv = rsqrtf(tot * (1.0f / 1024.0f) + 1e-5f);
        const float4 gv = ((const float4*)g1)[t];
        __bf16* o = zn + (size_t)row * 1024 + t * 4;
        o[0] = (__bf16)(v.x * inv * gv.x);
        o[1] = (__bf16)(v.y * inv * gv.y);
        o[2] = (__bf16)(v.z * inv * gv.z);
        o[3] = (__bf16)(v.w * inv * gv.w);
        return;
    }
    const float* src;
    __bf16* dst;
    int K, N, nx, t;
    if (id < 4096) {
        const int wsel = id >> 10;
        t = id & 1023;
        src = (wsel == 0) ? W_Q : (wsel == 1) ? W_K : (wsel == 2) ? W_V : W_O;
        dst = (wsel < 3) ? (WtQKV + (size_t)wsel * 1048576) : WtO;
        K = 1024; N = 1024; nx = 32;
    } else if (id < 8192) {
        t = id - 4096; src = W_fc; dst = Wtfc; K = 1024; N = 4096; nx = 128;
    } else {
        t = id - 8192; src = W_proj; dst = Wtproj; K = 4096; N = 1024; nx = 32;
    }
    const int n0 = (t % nx) * 32, k0 = (t / nx) * 32;

    __shared__ float tile[32][33];
    const int c = threadIdx.x & 31, r = threadIdx.x >> 5;
#pragma unroll
    for (int i = 0; i < 4; ++i)
        tile[r + 8 * i][c] = src[(size_t)(k0 + r + 8 * i) * N + n0 + c];
    __syncthreads();
#pragma unroll
    for (int i = 0; i < 4; ++i)
        dst[(size_t)(n0 + r + 8 * i) * K + k0 + c] = (__bf16)tile[c][r + 8 * i];
}

// ---------------- RMSNorm: fp32 [M][1024] -> bf16 [M][1024] -----------------
__global__ __launch_bounds__(256) void rmsnorm_kernel(
    const float* __restrict__ x, const float* __restrict__ gain,
    __bf16* __restrict__ out)
{
    const int row = blockIdx.x, t = threadIdx.x;
    const float4 v = ((const float4*)(x + (size_t)row * 1024))[t];
    float ss = v.x * v.x + v.y * v.y + v.z * v.z + v.w * v.w;
#pragma unroll
    for (int m = 1; m < 64; m <<= 1) ss += __shfl_xor(ss, m);
    __shared__ float red[4];
    const int wid = t >> 6, lane = t & 63;
    if (lane == 0) red[wid] = ss;
    __syncthreads();
    const float tot = red[0] + red[1] + red[2] + red[3];
    const float inv = rsqrtf(tot * (1.0f / 1024.0f) + 1e-5f);
    const float4 gv = ((const float4*)gain)[t];
    __bf16* o = out + (size_t)row * 1024 + t * 4;
    o[0] = (__bf16)(v.x * inv * gv.x);
    o[1] = (__bf16)(v.y * inv * gv.y);
    o[2] = (__bf16)(v.z * inv * gv.z);
    o[3] = (__bf16)(v.w * inv * gv.w);
}

// ---------------- reduce: out += p0 + p1 (bf16 partials, 8/thread) ----------
__global__ __launch_bounds__(256) void reduce_add_kernel(
    float* __restrict__ out, const __bf16* __restrict__ p0,
    const __bf16* __restrict__ p1, int n8)
{
    for (int i = blockIdx.x * 256 + threadIdx.x; i < n8; i += gridDim.x * 256) {
        const bf16x8 a = ((const bf16x8*)p0)[i];
        const bf16x8 b = ((const bf16x8*)p1)[i];
        float4 o0 = ((float4*)out)[2 * i];
        float4 o1 = ((float4*)out)[2 * i + 1];
        o0.x += (float)a[0] + (float)b[0]; o0.y += (float)a[1] + (float)b[1];
        o0.z += (float)a[2] + (float)b[2]; o0.w += (float)a[3] + (float)b[3];
        o1.x += (float)a[4] + (float)b[4]; o1.y += (float)a[5] + (float)b[5];
        o1.z += (float)a[6] + (float)b[6]; o1.w += (float)a[7] + (float)b[7];
        ((float4*)out)[2 * i] = o0;
        ((float4*)out)[2 * i + 1] = o1;
    }
}

// ---------------- C-write helper --------------------------------------------
template <int EPI>
__device__ __forceinline__ void epi_write(
    void* outp, const float* res, int N, int rowg, int colg, float v)
{
    if constexpr (EPI == 1) {
        const size_t idx = (size_t)rowg * N + colg;
        ((float*)outp)[idx] = res[idx] + v;
    } else if constexpr (EPI == 2) {
        // gelu, tanh form via exp2 (|diff vs erf-gelu| <~1e-3, << bf16 eps here)
        const size_t idx = (size_t)rowg * N + colg;
        const float u = v * (1.0f + 0.044715f * v * v) * 2.3022585093f;
        const float r = __builtin_amdgcn_rcpf(1.0f + exp2f(u));
        ((__bf16*)outp)[idx] = (__bf16)(v - v * r);
    }
}

// ---------------- 8-phase 256x256 GEMM (m201 template) ----------------------
// 2D XCD regions for the fc geometry (16x16 grid): 4m x 8n region per XCD.
template <int EPI>
__global__ __launch_bounds__(512, 2) void gemm256(
    const __bf16* __restrict__ A, const __bf16* __restrict__ Bt,
    void* __restrict__ outp, const float* __restrict__ res,
    int M, int N, int K)
{
    __shared__ __bf16 As[2][2][128 * 64];   // [dbuf][half][row*64+elem]
    __shared__ __bf16 Bs[2][2][128 * 64];
    const int tid = threadIdx.x;

    const int gx = gridDim.x, nwg = gx * gridDim.y;
    int bid = blockIdx.y * gx + blockIdx.x;
    int m0, n0;
    if (gx == 16 && gridDim.y == 16) {
        const int xcd = bid & 7, c = bid >> 3;   // c in [0,32)
        const int rm = xcd >> 1, rn = xcd & 1;   // 4 x 2 regions
        m0 = (rm * 4 + (c >> 3)) * 256;
        n0 = (rn * 8 + (c & 7)) * 256;
    } else {
        if ((nwg & 7) == 0) bid = (bid & 7) * (nwg >> 3) + (bid >> 3);
        m0 = (bid / gx) * 256; n0 = (bid % gx) * 256;
    }

    const int lane = tid & 63, w = tid >> 6;         // 8 waves
    const int wr = w >> 2, wc = w & 3;               // 2 x 4 wave grid
    const int lr = lane & 15, g = lane >> 4;
    const int srow8 = lane >> 3, schunk = (lane & 7) ^ srow8;
    const int xk = lr & 7;
    const int wch = wc >> 1, bro = (wc & 1) * 64;    // B half / row offset

    const __bf16* Ab = A + (size_t)m0 * K;
    const __bf16* Bb = Bt + (size_t)n0 * K;

    auto STG = [&](const __bf16* gb, __bf16* lds, int kt, int half) {
        const __bf16* src = gb + (size_t)(half * 128) * K + (kt << 6);
#pragma unroll
        for (int j = 0; j < 2; ++j) {
            const int sidx = j * 8 + w;
            GLDS16(src + (size_t)(sidx * 8 + srow8) * K + schunk * 8, lds + sidx * 512);
        }
    };

    f32x4 acc[8][4] = {};
    bf16x8 af[2][4], bf[2][4];

#define LAF(BUF, QM) do {                                                       \
    _Pragma("unroll") for (int i_ = 0; i_ < 4; ++i_)                            \
    _Pragma("unroll") for (int kk_ = 0; kk_ < 2; ++kk_)                         \
        af[kk_][i_] = *(const bf16x8*)&As[BUF][wr]                              \
            [((QM) * 64 + i_ * 16 + lr) * 64 + (((kk_ * 4 + g) ^ xk) << 3)];    \
    } while (0)

#define LBF(BUF, QN) do {                                                       \
    _Pragma("unroll") for (int i_ = 0; i_ < 2; ++i_)                            \
    _Pragma("unroll") for (int kk_ = 0; kk_ < 2; ++kk_)                         \
        bf[kk_][(QN) * 2 + i_] = *(const bf16x8*)&Bs[BUF][wch]                  \
            [(bro + ((QN) * 2 + i_) * 16 + lr) * 64 + (((kk_ * 4 + g) ^ xk) << 3)]; \
    } while (0)

#define MMQ(QM, QN) do {                                                        \
    __builtin_amdgcn_s_setprio(1);                                              \
    _Pragma("unroll") for (int kk_ = 0; kk_ < 2; ++kk_)                         \
    _Pragma("unroll") for (int i_ = 0; i_ < 4; ++i_)                            \
    _Pragma("unroll") for (int n_ = 0; n_ < 2; ++n_)                            \
        acc[(QM) * 4 + i_][(QN) * 2 + n_] = MFMA_16x16x32_BF16(                 \
            af[kk_][i_], bf[kk_][(QN) * 2 + n_], acc[(QM) * 4 + i_][(QN) * 2 + n_]); \
    __builtin_amdgcn_s_setprio(0);                                              \
    } while (0)

#define BAR()  __builtin_amdgcn_s_barrier()
#define VMC(N_) asm volatile("s_waitcnt vmcnt(" #N_ ")" ::: "memory")
#define SGB0() __builtin_amdgcn_sched_barrier(0)

    const int nt = K >> 6, niter = nt >> 1;

    STG(Ab, &As[0][0][0], 0, 0); STG(Ab, &As[0][1][0], 0, 1);
    STG(Bb, &Bs[0][0][0], 0, 0); STG(Bb, &Bs[0][1][0], 0, 1);
    STG(Bb, &Bs[1][0][0], 1, 0); STG(Bb, &Bs[1][1][0], 1, 1);

    for (int i = 0; i < niter - 1; ++i) {
        const int t1 = 2 * i + 1;
        STG(Ab, &As[1][0][0], t1, 0);
        VMC(6); BAR(); SGB0();
        LAF(0, 0); LBF(0, 0); MMQ(0, 0); BAR();
        LBF(0, 1); STG(Ab, &As[1][1][0], t1, 1); BAR(); MMQ(0, 1); BAR();
        LAF(0, 1); STG(Bb, &Bs[0][0][0], t1 + 1, 0); BAR(); MMQ(1, 0); BAR();
        STG(Bb, &Bs[0][1][0], t1 + 1, 1); BAR(); MMQ(1, 1); BAR();
        STG(Ab, &As[0][0][0], t1 + 1, 0);
        VMC(6); BAR(); SGB0();
        LAF(1, 0); LBF(1, 0); MMQ(0, 0); BAR();
        LBF(1, 1); STG(Ab, &As[0][1][0], t1 + 1, 1); BAR(); MMQ(0, 1); BAR();
        LAF(1, 1); STG(Bb, &Bs[1][0][0], t1 + 2, 0); BAR(); MMQ(1, 0); BAR();
        STG(Bb, &Bs[1][1][0], t1 + 2, 1); BAR(); MMQ(1, 1); BAR();
    }
    {   // peeled last iteration
        STG(Ab, &As[1][0][0], nt - 1, 0);
        VMC(6); BAR(); SGB0();
        LAF(0, 0); LBF(0, 0); MMQ(0, 0); BAR();
        LBF(0, 1); STG(Ab, &As[1][1][0], nt - 1, 1); BAR(); MMQ(0, 1); BAR();
        LAF(0, 1); BAR(); MMQ(1, 0); BAR();
        BAR(); MMQ(1, 1); BAR();
        VMC(0); BAR(); SGB0();
        LAF(1, 0); LBF(1, 0); MMQ(0, 0); BAR();
        LBF(1, 1); BAR(); MMQ(0, 1); BAR();
        LAF(1, 1); BAR(); MMQ(1, 0); BAR();
        BAR(); MMQ(1, 1); BAR();
    }
#undef LAF
#undef LBF
#undef MMQ
#undef BAR
#undef VMC
#undef SGB0

#pragma unroll
    for (int mi = 0; mi < 8; ++mi)
#pragma unroll
        for (int ni = 0; ni < 4; ++ni) {
            const int colg = n0 + wc * 64 + ni * 16 + lr;
#pragma unroll
            for (int r = 0; r < 4; ++r) {
                const int rowg = m0 + wr * 128 + mi * 16 + 4 * g + r;
                epi_write<EPI>(outp, res, N, rowg, colg, acc[mi][ni][r]);
            }
        }
}

// ---------------- 2-phase 128xBN dbuf GEMM (split-K capable) ----------------
// EPI 4 (QKV): Q/K written direct; V staged through LDS transpose tile.
// EPI 5: store bf16 partial (part 0 -> outp, part 1 -> res cast).
template <int BM, int BN, int EPI>
__global__ __launch_bounds__(256) void gemm_bf16(
    const __bf16* __restrict__ A, const __bf16* __restrict__ Bt,
    void* __restrict__ outp, const float* __restrict__ res,
    int M, int N, int K, int Kld)
{
    __shared__ __bf16 As[2][BM * 64];
    __shared__ __bf16 Bs[2][BN * 64];
    const int tid = threadIdx.x;

    const int gx = gridDim.x, nwg = gx * gridDim.y;
    int bid = blockIdx.y * gx + blockIdx.x;
    int m0, n0;
    if constexpr (EPI == 4) {
        // gx = 32, gy = 32: 2D regions of 8m x 16n per XCD
        const int xcd = bid & 7, c = bid >> 3;   // c in [0,128)
        const int rm = xcd >> 1, rn = xcd & 1;   // 4 x 2 regions
        m0 = (rm * 8 + (c >> 4)) * BM;
        n0 = (rn * 16 + (c & 15)) * BN;
    } else {
        if ((nwg & 7) == 0) bid = (bid & 7) * (nwg >> 3) + (bid >> 3);
        m0 = (bid / gx) * BM; n0 = (bid % gx) * BN;
    }

    const int lane = tid & 63, w = tid >> 6;
    const int wm = w >> 1, wn = w & 1;
    const int lr = lane & 15, g = lane >> 4;
    const int srow = lane >> 3;
    const int scol = ((lane & 7) ^ srow) * 8;
    const int xr8 = lr & 7;

    constexpr int MI = BM / 32, NI = BN / 32;
    f32x4 acc[MI][NI] = {};

    const __bf16* Abase = A + (size_t)m0 * Kld + blockIdx.z * K;
    const __bf16* Bbase = Bt + (size_t)n0 * Kld + blockIdx.z * K;

    auto STAGE = [&](int kb, int buf) {
#pragma unroll
        for (int j = 0; j < BM / 32; ++j) {
            const int s = j * 4 + w;
            GLDS16(Abase + (size_t)(s * 8 + srow) * Kld + kb + scol, &As[buf][s * 512]);
        }
#pragma unroll
        for (int j = 0; j < BN / 32; ++j) {
            const int s = j * 4 + w;
            GLDS16(Bbase + (size_t)(s * 8 + srow) * Kld + kb + scol, &Bs[buf][s * 512]);
        }
    };

    const int nt = K >> 6;
    STAGE(0, 0);
    __syncthreads();

    for (int t = 0; t < nt; ++t) {
        const int cur = t & 1;
        if (t + 1 < nt) STAGE((t + 1) << 6, cur ^ 1);

        bf16x8 af[2][MI], bfr[2][NI];
#pragma unroll
        for (int kk = 0; kk < 2; ++kk) {
#pragma unroll
            for (int i = 0; i < MI; ++i)
                af[kk][i] = *(const bf16x8*)
                    &As[cur][(wm * (BM / 2) + i * 16 + lr) * 64 + (((kk * 4 + g) ^ xr8) << 3)];
#pragma unroll
            for (int i = 0; i < NI; ++i)
                bfr[kk][i] = *(const bf16x8*)
                    &Bs[cur][(wn * (BN / 2) + i * 16 + lr) * 64 + (((kk * 4 + g) ^ xr8) << 3)];
        }
#pragma unroll
        for (int kk = 0; kk < 2; ++kk)
#pragma unroll
            for (int mi = 0; mi < MI; ++mi)
#pragma unroll
                for (int ni = 0; ni < NI; ++ni)
                    acc[mi][ni] = MFMA_16x16x32_BF16(af[kk][mi], bfr[kk][ni], acc[mi][ni]);
        if (t + 1 < nt) __syncthreads();
    }

    if constexpr (EPI == 4) {
        __bf16* vtile = (__bf16*)As;                 // 32KB >= BN*128*2B
        const bool hasV = (n0 + BN > 2048);
        if (hasV) __syncthreads();                   // As free for reuse
#pragma unroll
        for (int mi = 0; mi < MI; ++mi)
#pragma unroll
            for (int ni = 0; ni < NI; ++ni) {
                const int colg = n0 + wn * (BN / 2) + ni * 16 + lr;
#pragma unroll
                for (int r = 0; r < 4; ++r) {
                    const int rowg = m0 + wm * (BM / 2) + mi * 16 + 4 * g + r;
                    const float v = acc[mi][ni][r];
                    if (colg < 2048) {
                        ((__bf16*)outp)[(size_t)(colg >> 10) * 4194304 +
                                        (size_t)rowg * 1024 + (colg & 1023)] = (__bf16)v;
                    } else {
                        // stage into LDS, pre-permuted: trow 16h+4g'+j -> 8g'+4h+j
                        const int trow = rowg - m0;
                        const int r32 = trow & 31;
                        const int p = ((r32 & 12) << 1) | ((r32 >> 2) & 4) | (r32 & 3);
                        vtile[(colg - n0) * 128 + (trow & ~31) + p] = (__bf16)v;
                    }
                }
            }
        if (hasV) {
            __syncthreads();
            const int vstart = (2048 > n0) ? (2048 - n0) : 0;
            const int nvec = (BN - vstart) * 16;     // bf16x8 vectors
            __bf16* base = (__bf16*)outp;
            const size_t vt0 = 8388608 + (size_t)((m0 >> 11) * 16) * 64 * 2048 +
                               (m0 & 2047);
            for (int v = tid; v < nvec; v += 256) {
                const int vc = vstart + (v >> 4);
                const int t8 = (v & 15) << 3;
                const int cg = (n0 + vc) & 1023;
                const size_t idx = vt0 + ((size_t)(cg >> 6) * 64 + (cg & 63)) * 2048 + t8;
                *(bf16x8*)&base[idx] = *(const bf16x8*)&vtile[vc * 128 + t8];
            }
        }
    } else {
#pragma unroll
        for (int mi = 0; mi < MI; ++mi)
#pragma unroll
            for (int ni = 0; ni < NI; ++ni) {
                const int colg = n0 + wn * (BN / 2) + ni * 16 + lr;
#pragma unroll
                for (int r = 0; r < 4; ++r) {
                    const int rowg = m0 + wm * (BM / 2) + mi * 16 + 4 * g + r;
                    const float v = acc[mi][ni][r];
                    if constexpr (EPI == 5) {
                        __bf16* pout = (blockIdx.z == 0) ? (__bf16*)outp
                                                         : (__bf16*)(void*)res;
                        pout[(size_t)rowg * N + colg] = (__bf16)v;
                    } else {
                        epi_write<EPI>(outp, res, N, rowg, colg, v);
                    }
                }
            }
    }
}

// ---------------- Flash-style causal attention (split-KV halves) ------------
// Grid: 1024 blocks. bx -> half = bx&1, u' = bx>>1, j = u'>>5, bh = u'&31,
// qc = 15 - j (longest units dispatch first -> backfill). Unit (bh,qc) covers
// q rows [qc*128, qc*128+128); its qc+1 kv steps split at h0 = (qc+2)/2.
// Each half writes unnormalized O (bf16, D-layout rows), row-sum S (D-layout)
// and the per-row softmax max m (row = lr, per the mfma(K,Q) D-layout).
__global__ __launch_bounds__(512) void attn_kernel(
    const __bf16* __restrict__ Q, const __bf16* __restrict__ Kb,
    const __bf16* __restrict__ Vt, __bf16* __restrict__ Op,
    float* __restrict__ Sp, float* __restrict__ Mp)
{
    const int Dm = 1024, T = 2048;
    const int tid = threadIdx.x;
    const int w = tid >> 6, lane = tid & 63;
    const int lr = lane & 15, g = lane >> 4;
    const int bx = blockIdx.x;
    const int half = bx & 1, up = bx >> 1;
    const int j = up >> 5, bh = up & 31, b = bh >> 4, h = bh & 15;
    const int qc = 15 - j;
    const int qbase = qc * 128 + w * 16;
    const size_t rowoff = (size_t)b * T;
    const __bf16* Qp = Q + rowoff * Dm + h * 64;
    const __bf16* Kp = Kb + rowoff * Dm + h * 64;
    const __bf16* Vtp = Vt + (size_t)bh * 64 * 2048;

    __shared__ __bf16 Ks[2][128 * 64];
    __shared__ __bf16 Vs[2][64 * 128];

    bf16x8 qf0 = *(const bf16x8*)&Qp[(size_t)(qbase + lr) * Dm + g * 8];
    bf16x8 qf1 = *(const bf16x8*)&Qp[(size_t)(qbase + lr) * Dm + 32 + g * 8];
    const float qsc = 0.125f * 1.44269504088896340736f;
#pragma unroll
    for (int jj = 0; jj < 8; ++jj) {
        qf0[jj] = (__bf16)((float)qf0[jj] * qsc);
        qf1[jj] = (__bf16)((float)qf1[jj] * qsc);
    }
    bf16x8 ones;
#pragma unroll
    for (int jj = 0; jj < 8; ++jj) ones[jj] = (__bf16)1.0f;

    const int ksrow = lane >> 3;
    const int kschunk = (lane & 7) ^ ksrow;
    const int vsrow = lane >> 4;                    // 0..3

    f32x4 acc[4] = {};
    f32x4 accS = {};                                // row-sum accumulator
    float m_s = 0.0f;                               // log2-domain running max
    const int h0 = (qc + 2) >> 1;
    const int t0 = half ? h0 : 0;
    const int t1 = half ? (qc + 1) : h0;
    const f32x4 zacc = {0.0f, 0.0f, 0.0f, 0.0f};
    const int x8 = lr & 7;                          // K read chunk XOR
    const int qg = qbase + lr;

    auto STAGE = [&](int kvb, int buf) {
#pragma unroll
        for (int jj = 0; jj < 2; ++jj) {
            const int krow = w * 16 + jj * 8;
            GLDS16(Kp + (size_t)(kvb + krow + ksrow) * Dm + kschunk * 8,
                   &Ks[buf][krow * 64]);
            const int vrow = w * 8 + jj * 4;
            const int vchunk = (lane & 15) ^ ((vrow + vsrow) & 15);
            GLDS16(Vtp + (size_t)(vrow + vsrow) * T + kvb + vchunk * 8,
                   &Vs[buf][vrow * 128]);
        }
    };

    if (t0 < t1) {
        STAGE(t0 * 128, t0 & 1);
        __syncthreads();
    }

    for (int t = t0; t < t1; ++t) {
        const int kvb = t * 128, cur = t & 1;
        if (t + 1 < t1) STAGE(kvb + 128, cur ^ 1);

        float sv[8][4];
        if (t < qc) {
            // ---- FULL fast path: whole 128-kv tile live, no mask logic ----
#pragma unroll
            for (int s4 = 0; s4 < 8; ++s4) {
                const int row = s4 * 16 + lr;
                const bf16x8 kfa = *(const bf16x8*)&Ks[cur][row * 64 + ((g ^ x8) << 3)];
                const bf16x8 kfb = *(const bf16x8*)&Ks[cur][row * 64 + (((4 + g) ^ x8) << 3)];
                f32x4 st = MFMA_16x16x32_BF16(kfa, qf0, zacc);
                st = MFMA_16x16x32_BF16(kfb, qf1, st);
#pragma unroll
                for (int r = 0; r < 4; ++r) sv[s4][r] = st[r];
            }
        } else {
            // ---- diagonal step: per-subtile guards + causal mask ----
#pragma unroll
            for (int s4 = 0; s4 < 8; ++s4) {
                const int kv0 = kvb + s4 * 16;
                if (kv0 <= qbase + 15) {
                    const int row = s4 * 16 + lr;
                    const bf16x8 kfa = *(const bf16x8*)&Ks[cur][row * 64 + ((g ^ x8) << 3)];
                    const bf16x8 kfb = *(const bf16x8*)&Ks[cur][row * 64 + (((4 + g) ^ x8) << 3)];
                    f32x4 st = MFMA_16x16x32_BF16(kfa, qf0, zacc);
                    st = MFMA_16x16x32_BF16(kfb, qf1, st);
                    const bool domask = (kv0 + 15 > qbase);
#pragma unroll
                    for (int r = 0; r < 4; ++r) {
                        float x = st[r];
                        if (domask && (kv0 + 4 * g + r > qg)) x = -__builtin_inff();
                        sv[s4][r] = x;
                    }
                } else {
#pragma unroll
                    for (int r = 0; r < 4; ++r) sv[s4][r] = -__builtin_inff();
                }
            }
        }

        // ---- deferred online softmax (log2 domain); v_max3 tree ----
        float tml = fmax3(sv[0][0], sv[0][1], sv[0][2]);
        tml = fmax3(tml, sv[0][3], sv[1][0]);
        tml = fmax3(tml, sv[1][1], sv[1][2]);
        tml = fmax3(tml, sv[1][3], sv[2][0]);
        tml = fmax3(tml, sv[2][1], sv[2][2]);
        tml = fmax3(tml, sv[2][3], sv[3][0]);
        tml = fmax3(tml, sv[3][1], sv[3][2]);
        tml = fmax3(tml, sv[3][3], sv[4][0]);
        tml = fmax3(tml, sv[4][1], sv[4][2]);
        tml = fmax3(tml, sv[4][3], sv[5][0]);
        tml = fmax3(tml, sv[5][1], sv[5][2]);
        tml = fmax3(tml, sv[5][3], sv[6][0]);
        tml = fmax3(tml, sv[6][1], sv[6][2]);
        tml = fmax3(tml, sv[6][3], sv[7][0]);
        tml = fmax3(tml, sv[7][1], sv[7][2]);
        tml = fmaxf(tml, sv[7][3]);

        if (!__all(tml - m_s <= 11.5f)) {
            float tm = fmaxf(tml, __shfl_xor(tml, 16));
            tm = fmaxf(tm, __shfl_xor(tm, 32));
            const float m_new = fmaxf(m_s, tm);
            const float corr = exp2f(m_s - m_new);
            float cr[4];
#pragma unroll
            for (int r = 0; r < 4; ++r) cr[r] = __shfl(corr, 4 * g + r);
#pragma unroll
            for (int ct = 0; ct < 4; ++ct) {
                acc[ct][0] *= cr[0]; acc[ct][1] *= cr[1];
                acc[ct][2] *= cr[2]; acc[ct][3] *= cr[3];
            }
            accS[0] *= cr[0]; accS[1] *= cr[1];
            accS[2] *= cr[2]; accS[3] *= cr[3];
            m_s = m_new;
        }

#pragma unroll
        for (int s4 = 0; s4 < 8; ++s4)
#pragma unroll
            for (int r = 0; r < 4; ++r)
                sv[s4][r] = exp2f(sv[s4][r] - m_s);

        // ---- PV + ones-column row-sum ----
        bf16x8 pa[4];
#pragma unroll
        for (int s = 0; s < 4; ++s)
#pragma unroll
            for (int r = 0; r < 4; ++r) {
                pa[s][r] = (__bf16)sv[2 * s][r];
                pa[s][4 + r] = (__bf16)sv[2 * s + 1][r];
            }
        if (t < qc) {
#pragma unroll
            for (int s = 0; s < 4; ++s)
                accS = MFMA_16x16x32_BF16(pa[s], ones, accS);
#pragma unroll
            for (int ct = 0; ct < 4; ++ct) {
                const __bf16* vrow = &Vs[cur][(ct * 16 + lr) * 128];
#pragma unroll
                for (int s = 0; s < 4; ++s) {
                    const bf16x8 vf = *(const bf16x8*)&vrow[(((s * 4 + g) ^ lr) << 3)];
                    acc[ct] = MFMA_16x16x32_BF16(pa[s], vf, acc[ct]);
                }
            }
        } else {
#pragma unroll
            for (int s = 0; s < 4; ++s)
                if (kvb + s * 32 <= qbase + 15)
                    accS = MFMA_16x16x32_BF16(pa[s], ones, accS);
#pragma unroll
            for (int ct = 0; ct < 4; ++ct) {
                const __bf16* vrow = &Vs[cur][(ct * 16 + lr) * 128];
#pragma unroll
                for (int s = 0; s < 4; ++s) {
                    if (kvb + s * 32 <= qbase + 15) {
                        const bf16x8 vf = *(const bf16x8*)&vrow[(((s * 4 + g) ^ lr) << 3)];
                        acc[ct] = MFMA_16x16x32_BF16(pa[s], vf, acc[ct]);
                    }
                }
            }
        }
        __syncthreads();
    }

    // ---- write partials ----
    // O, S are D-layout (row = w*16 + 4g + r). m_s belongs to softmax row
    // lr (mfma(K,Q) puts q-row in the column index) -> index Mp by lr.
    const int hb = ((bh * 16 + qc) << 1) | half;
    __bf16* Oh = Op + (size_t)hb * 8192;            // [128][64]
#pragma unroll
    for (int ct = 0; ct < 4; ++ct)
#pragma unroll
        for (int r = 0; r < 4; ++r)
            Oh[(w * 16 + 4 * g + r) * 64 + ct * 16 + lr] = (__bf16)acc[ct][r];
    if (lr == 0) {
#pragma unroll
        for (int r = 0; r < 4; ++r)
            Sp[hb * 128 + w * 16 + 4 * g + r] = accS[r];
    }
    if (g == 0) {                                   // BUG FIX vs r18
        Mp[hb * 128 + w * 16 + lr] = m_s;
    }
}

// ---------------- attn combine: ctx = (OA*2^mA + OB*2^mB)/(SA*2^mA+SB*2^mB) -
__global__ __launch_bounds__(256) void attn_combine_kernel(
    const __bf16* __restrict__ Op, const float* __restrict__ Sp,
    const float* __restrict__ Mp, __bf16* __restrict__ ctx)
{
    const int u = blockIdx.x;                       // 512 units
    const int bh = u >> 4, qc = u & 15;
    const int b = bh >> 4, h = bh & 15;
    const int row = threadIdx.x >> 1, dh = (threadIdx.x & 1) * 32;
    const int hb0 = u * 2, hb1 = hb0 + 1;
    const float mA = Mp[hb0 * 128 + row], mB = Mp[hb1 * 128 + row];
    const float M = fmaxf(mA, mB);
    const float eA = exp2f(mA - M), eB = exp2f(mB - M);
    const float den = Sp[hb0 * 128 + row] * eA + Sp[hb1 * 128 + row] * eB;
    const float inv = __builtin_amdgcn_rcpf(den);
    const float fA = eA * inv, fB = eB * inv;
    const __bf16* OA = Op + (size_t)hb0 * 8192 + row * 64 + dh;
    const __bf16* OB = Op + (size_t)hb1 * 8192 + row * 64 + dh;
    __bf16* co = ctx + ((size_t)(b * 2048 + qc * 128 + row)) * 1024 + h * 64 + dh;
#pragma unroll
    for (int k = 0; k < 4; ++k) {
        const bf16x8 a = *(const bf16x8*)&OA[k * 8];
        const bf16x8 bv = *(const bf16x8*)&OB[k * 8];
        bf16x8 o;
#pragma unroll
        for (int e = 0; e < 8; ++e)
            o[e] = (__bf16)((float)a[e] * fA + (float)bv[e] * fB);
        *(bf16x8*)&co[k * 8] = o;
    }
}

// ---------------------------------------------------------------------------
extern "C" void kernel_launch(void* const* d_in, const int* in_sizes, int n_in,
                              void* d_out, int out_size, void* d_ws, size_t ws_size,
                              hipStream_t stream)
{
    (void)in_sizes; (void)n_in; (void)out_size; (void)ws_size;
    const float* z      = (const float*)d_in[0];
    const float* W_Q    = (const float*)d_in[1];
    const float* W_K    = (const float*)d_in[2];
    const float* W_V    = (const float*)d_in[3];
    const float* W_O    = (const float*)d_in[4];
    const float* W_fc   = (const float*)d_in[5];
    const float* W_proj = (const float*)d_in[6];
    const float* g1     = (const float*)d_in[7];
    const float* g2     = (const float*)d_in[8];
    float* out = (float*)d_out;

    char* ws = (char*)d_ws;
    const size_t MB = (size_t)1 << 20;
    __bf16* WtQKV  = (__bf16*)(ws + 0 * MB);   // [3072][1024]
    __bf16* WtO    = (__bf16*)(ws + 6 * MB);
    __bf16* Wtfc   = (__bf16*)(ws + 8 * MB);
    __bf16* Wtproj = (__bf16*)(ws + 16 * MB);
    __bf16* zn     = (__bf16*)(ws + 24 * MB);  // reused as ctx
    __bf16* Qb     = (__bf16*)(ws + 32 * MB);  // QKV out base; reused as h
    __bf16* Kbuf   = (__bf16*)(ws + 40 * MB);
    __bf16* Vtb    = (__bf16*)(ws + 48 * MB);
    __bf16* Opart  = (__bf16*)(ws + 56 * MB);  // 16MB attn O-partials
    float*  Spart  = (float*)(ws + 0 * MB);    // 512KB (dead WtQKV)
    float*  Mpart  = (float*)(ws + 0 * MB + 524288);
    __bf16* ffn1   = (__bf16*)(ws + 40 * MB);  // overlaps K,Vt,Op (post-attn)
    __bf16* part0  = (__bf16*)(ws + 0 * MB);   // 8MB bf16: dead WtQKV/WtO/Sp/Mp
    __bf16* part1  = (__bf16*)(ws + 24 * MB);  // 8MB bf16: dead zn/ctx
    __bf16* ctx    = zn;
    __bf16* hb     = Qb;

    const int Tt = 2048, Dm = 1024, Bb = 2, M = Bb * Tt, DFF = 4096;
    const dim3 blk256(256), blk512(512);

    // fused: weight transposes + rmsnorm(z, g1) -> zn
    fused_head_kernel<<<16384, blk256, 0, stream>>>(
        W_Q, W_K, W_V, W_O, W_fc, W_proj, WtQKV, WtO, Wtfc, Wtproj, z, g1, zn);

    // Fused QKV (2-phase 128x96, 1024 blocks, LDS-transposed V epilogue)
    gemm_bf16<128, 96, 4><<<dim3(32, 32), blk256, 0, stream>>>(
        zn, WtQKV, Qb, nullptr, M, 3072, Dm, Dm);

    // attention split-KV halves (1024 blocks) + combine
    attn_kernel<<<1024, blk512, 0, stream>>>(Qb, Kbuf, Vtb, Opart, Spart, Mpart);
    attn_combine_kernel<<<512, blk256, 0, stream>>>(Opart, Spart, Mpart, ctx);

    // z2 = z + ctx @ W_O  -> d_out (fp32)
    gemm_bf16<128, 64, 1><<<dim3(16, 32), blk256, 0, stream>>>(
        ctx, WtO, out, z, M, Dm, Dm, Dm);

    // h = rmsnorm(z2, g2)
    rmsnorm_kernel<<<M, blk256, 0, stream>>>(out, g2, hb);

    // ffn1 = gelu(h @ W_fc) (8-phase 256^2, 2D XCD regions)
    gemm256<2><<<dim3(16, 16), blk512, 0, stream>>>(
        hb, Wtfc, ffn1, nullptr, M, DFF, Dm);

    // proj split-K=2 (128x128, 512 blocks): bf16 partials p0/p1
    gemm_bf16<128, 128, 5><<<dim3(8, 32, 2), blk256, 0, stream>>>(
        ffn1, Wtproj, part0, (const float*)part1, M, Dm, DFF / 2, DFF);

    // d_out += p0 + p1  (bf16 partials, 8 elems/thread)
    reduce_add_kernel<<<2048, blk256, 0, stream>>>(out, part0, part1, M * Dm / 8);
}

// Round 23
// 222.844 us; speedup vs baseline: 1.0448x; 1.0448x over previous
//
#include <hip/hip_runtime.h>
#include <hip/hip_bf16.h>
#include <math.h>

// ---------------------------------------------------------------------------
// GPT block on MI355X (gfx950). bf16 MFMA compute, fp32 accumulate.
// Workspace layout (MB = 1<<20), total 72 MB:
//   [ 0, 6)  WtQKV  bf16 [3072][1024]   -- dead after QKV; partial0 (bf16 8MB)
//   [ 6, 8)  WtO    bf16 [1024][1024]
//   [ 8,16)  Wtfc   bf16 [4096][1024]
//   [16,24)  Wtproj bf16 [1024][4096]
//   [24,32)  zn / ctx   bf16            -- dead after O-proj; partial1 (bf16)
//   [32,40)  Q / h      bf16
//   [40,48)  K          bf16
//   [48,56)  Vt         bf16 [32][64][2048]  (V transposed, kv-permuted)
//   [40,72)  ffn1       bf16 [4096][4096]  (overlaps K,Vt — dead after attn)
// QKV: 2-phase 128x96, LDS-transposed V epilogue (coalesced Vt stores).
// fc: 8-phase 256^2 + 2D XCD regions. proj: split-K=2 bf16 partials + reduce.
// attn: 8-wave KVBLK=128, FULL fast path, deferred softmax; row-sum computed
// on the MFMA pipe via an all-ones B operand (lands directly in D-layout).
// (r22's split-KV attention passed correctness but was ~10us slower: extra
// Q re-reads + partial traffic + combine pass with no makespan gain.)
// ---------------------------------------------------------------------------

typedef __bf16 bf16x8 __attribute__((ext_vector_type(8)));
typedef float  f32x4  __attribute__((ext_vector_type(4)));

#define MFMA_16x16x32_BF16(A, B, C) __builtin_amdgcn_mfma_f32_16x16x32_bf16((A), (B), (C), 0, 0, 0)

#define GLDS16(g, l) __builtin_amdgcn_global_load_lds( \
    (const __attribute__((address_space(1))) void*)(g), \
    (__attribute__((address_space(3))) void*)(l), 16, 0, 0)

__device__ __forceinline__ float fmax3(float a, float b, float c) {
    return fmaxf(fmaxf(a, b), c);   // clang fuses to v_max3_f32
}

// ---------------- fused head: 6 weight transposes + rmsnorm(z,g1) -----------
__global__ __launch_bounds__(256) void fused_head_kernel(
    const float* __restrict__ W_Q, const float* __restrict__ W_K,
    const float* __restrict__ W_V, const float* __restrict__ W_O,
    const float* __restrict__ W_fc, const float* __restrict__ W_proj,
    __bf16* __restrict__ WtQKV, __bf16* __restrict__ WtO,
    __bf16* __restrict__ Wtfc, __bf16* __restrict__ Wtproj,
    const float* __restrict__ z, const float* __restrict__ g1,
    __bf16* __restrict__ zn)
{
    const int id = blockIdx.x;
    if (id >= 12288) {
        const int row = id - 12288, t = threadIdx.x;
        const float4 v = ((const float4*)(z + (size_t)row * 1024))[t];
        float ss = v.x * v.x + v.y * v.y + v.z * v.z + v.w * v.w;
#pragma unroll
        for (int m = 1; m < 64; m <<= 1) ss += __shfl_xor(ss, m);
        __shared__ float red[4];
        const int wid = t >> 6, lane = t & 63;
        if (lane == 0) red[wid] = ss;
        __syncthreads();
        const float tot = red[0] + red[1] + red[2] + red[3];
        const float inv = rsqrtf(tot * (1.0f / 1024.0f) + 1e-5f);
        const float4 gv = ((const float4*)g1)[t];
        __bf16* o = zn + (size_t)row * 1024 + t * 4;
        o[0] = (__bf16)(v.x * inv * gv.x);
        o[1] = (__bf16)(v.y * inv * gv.y);
        o[2] = (__bf16)(v.z * inv * gv.z);
        o[3] = (__bf16)(v.w * inv * gv.w);
        return;
    }
    const float* src;
    __bf16* dst;
    int K, N, nx, t;
    if (id < 4096) {
        const int wsel = id >> 10;
        t = id & 1023;
        src = (wsel == 0) ? W_Q : (wsel == 1) ? W_K : (wsel == 2) ? W_V : W_O;
        dst = (wsel < 3) ? (WtQKV + (size_t)wsel * 1048576) : WtO;
        K = 1024; N = 1024; nx = 32;
    } else if (id < 8192) {
        t = id - 4096; src = W_fc; dst = Wtfc; K = 1024; N = 4096; nx = 128;
    } else {
        t = id - 8192; src = W_proj; dst = Wtproj; K = 4096; N = 1024; nx = 32;
    }
    const int n0 = (t % nx) * 32, k0 = (t / nx) * 32;

    __shared__ float tile[32][33];
    const int c = threadIdx.x & 31, r = threadIdx.x >> 5;
#pragma unroll
    for (int i = 0; i < 4; ++i)
        tile[r + 8 * i][c] = src[(size_t)(k0 + r + 8 * i) * N + n0 + c];
    __syncthreads();
#pragma unroll
    for (int i = 0; i < 4; ++i)
        dst[(size_t)(n0 + r + 8 * i) * K + k0 + c] = (__bf16)tile[c][r + 8 * i];
}

// ---------------- RMSNorm: fp32 [M][1024] -> bf16 [M][1024] -----------------
__global__ __launch_bounds__(256) void rmsnorm_kernel(
    const float* __restrict__ x, const float* __restrict__ gain,
    __bf16* __restrict__ out)
{
    const int row = blockIdx.x, t = threadIdx.x;
    const float4 v = ((const float4*)(x + (size_t)row * 1024))[t];
    float ss = v.x * v.x + v.y * v.y + v.z * v.z + v.w * v.w;
#pragma unroll
    for (int m = 1; m < 64; m <<= 1) ss += __shfl_xor(ss, m);
    __shared__ float red[4];
    const int wid = t >> 6, lane = t & 63;
    if (lane == 0) red[wid] = ss;
    __syncthreads();
    const float tot = red[0] + red[1] + red[2] + red[3];
    const float inv = rsqrtf(tot * (1.0f / 1024.0f) + 1e-5f);
    const float4 gv = ((const float4*)gain)[t];
    __bf16* o = out + (size_t)row * 1024 + t * 4;
    o[0] = (__bf16)(v.x * inv * gv.x);
    o[1] = (__bf16)(v.y * inv * gv.y);
    o[2] = (__bf16)(v.z * inv * gv.z);
    o[3] = (__bf16)(v.w * inv * gv.w);
}

// ---------------- reduce: out += p0 + p1 (bf16 partials, 8/thread) ----------
__global__ __launch_bounds__(256) void reduce_add_kernel(
    float* __restrict__ out, const __bf16* __restrict__ p0,
    const __bf16* __restrict__ p1, int n8)
{
    for (int i = blockIdx.x * 256 + threadIdx.x; i < n8; i += gridDim.x * 256) {
        const bf16x8 a = ((const bf16x8*)p0)[i];
        const bf16x8 b = ((const bf16x8*)p1)[i];
        float4 o0 = ((float4*)out)[2 * i];
        float4 o1 = ((float4*)out)[2 * i + 1];
        o0.x += (float)a[0] + (float)b[0]; o0.y += (float)a[1] + (float)b[1];
        o0.z += (float)a[2] + (float)b[2]; o0.w += (float)a[3] + (float)b[3];
        o1.x += (float)a[4] + (float)b[4]; o1.y += (float)a[5] + (float)b[5];
        o1.z += (float)a[6] + (float)b[6]; o1.w += (float)a[7] + (float)b[7];
        ((float4*)out)[2 * i] = o0;
        ((float4*)out)[2 * i + 1] = o1;
    }
}

// ---------------- C-write helper --------------------------------------------
template <int EPI>
__device__ __forceinline__ void epi_write(
    void* outp, const float* res, int N, int rowg, int colg, float v)
{
    if constexpr (EPI == 1) {
        const size_t idx = (size_t)rowg * N + colg;
        ((float*)outp)[idx] = res[idx] + v;
    } else if constexpr (EPI == 2) {
        // gelu, tanh form via exp2 (|diff vs erf-gelu| <~1e-3, << bf16 eps here)
        const size_t idx = (size_t)rowg * N + colg;
        const float u = v * (1.0f + 0.044715f * v * v) * 2.3022585093f;
        const float r = __builtin_amdgcn_rcpf(1.0f + exp2f(u));
        ((__bf16*)outp)[idx] = (__bf16)(v - v * r);
    }
}

// ---------------- 8-phase 256x256 GEMM (m201 template) ----------------------
// 2D XCD regions for the fc geometry (16x16 grid): 4m x 8n region per XCD.
template <int EPI>
__global__ __launch_bounds__(512, 2) void gemm256(
    const __bf16* __restrict__ A, const __bf16* __restrict__ Bt,
    void* __restrict__ outp, const float* __restrict__ res,
    int M, int N, int K)
{
    __shared__ __bf16 As[2][2][128 * 64];   // [dbuf][half][row*64+elem]
    __shared__ __bf16 Bs[2][2][128 * 64];
    const int tid = threadIdx.x;

    const int gx = gridDim.x, nwg = gx * gridDim.y;
    int bid = blockIdx.y * gx + blockIdx.x;
    int m0, n0;
    if (gx == 16 && gridDim.y == 16) {
        const int xcd = bid & 7, c = bid >> 3;   // c in [0,32)
        const int rm = xcd >> 1, rn = xcd & 1;   // 4 x 2 regions
        m0 = (rm * 4 + (c >> 3)) * 256;
        n0 = (rn * 8 + (c & 7)) * 256;
    } else {
        if ((nwg & 7) == 0) bid = (bid & 7) * (nwg >> 3) + (bid >> 3);
        m0 = (bid / gx) * 256; n0 = (bid % gx) * 256;
    }

    const int lane = tid & 63, w = tid >> 6;         // 8 waves
    const int wr = w >> 2, wc = w & 3;               // 2 x 4 wave grid
    const int lr = lane & 15, g = lane >> 4;
    const int srow8 = lane >> 3, schunk = (lane & 7) ^ srow8;
    const int xk = lr & 7;
    const int wch = wc >> 1, bro = (wc & 1) * 64;    // B half / row offset

    const __bf16* Ab = A + (size_t)m0 * K;
    const __bf16* Bb = Bt + (size_t)n0 * K;

    auto STG = [&](const __bf16* gb, __bf16* lds, int kt, int half) {
        const __bf16* src = gb + (size_t)(half * 128) * K + (kt << 6);
#pragma unroll
        for (int j = 0; j < 2; ++j) {
            const int sidx = j * 8 + w;
            GLDS16(src + (size_t)(sidx * 8 + srow8) * K + schunk * 8, lds + sidx * 512);
        }
    };

    f32x4 acc[8][4] = {};
    bf16x8 af[2][4], bf[2][4];

#define LAF(BUF, QM) do {                                                       \
    _Pragma("unroll") for (int i_ = 0; i_ < 4; ++i_)                            \
    _Pragma("unroll") for (int kk_ = 0; kk_ < 2; ++kk_)                         \
        af[kk_][i_] = *(const bf16x8*)&As[BUF][wr]                              \
            [((QM) * 64 + i_ * 16 + lr) * 64 + (((kk_ * 4 + g) ^ xk) << 3)];    \
    } while (0)

#define LBF(BUF, QN) do {                                                       \
    _Pragma("unroll") for (int i_ = 0; i_ < 2; ++i_)                            \
    _Pragma("unroll") for (int kk_ = 0; kk_ < 2; ++kk_)                         \
        bf[kk_][(QN) * 2 + i_] = *(const bf16x8*)&Bs[BUF][wch]                  \
            [(bro + ((QN) * 2 + i_) * 16 + lr) * 64 + (((kk_ * 4 + g) ^ xk) << 3)]; \
    } while (0)

#define MMQ(QM, QN) do {                                                        \
    __builtin_amdgcn_s_setprio(1);                                              \
    _Pragma("unroll") for (int kk_ = 0; kk_ < 2; ++kk_)                         \
    _Pragma("unroll") for (int i_ = 0; i_ < 4; ++i_)                            \
    _Pragma("unroll") for (int n_ = 0; n_ < 2; ++n_)                            \
        acc[(QM) * 4 + i_][(QN) * 2 + n_] = MFMA_16x16x32_BF16(                 \
            af[kk_][i_], bf[kk_][(QN) * 2 + n_], acc[(QM) * 4 + i_][(QN) * 2 + n_]); \
    __builtin_amdgcn_s_setprio(0);                                              \
    } while (0)

#define BAR()  __builtin_amdgcn_s_barrier()
#define VMC(N_) asm volatile("s_waitcnt vmcnt(" #N_ ")" ::: "memory")
#define SGB0() __builtin_amdgcn_sched_barrier(0)

    const int nt = K >> 6, niter = nt >> 1;

    STG(Ab, &As[0][0][0], 0, 0); STG(Ab, &As[0][1][0], 0, 1);
    STG(Bb, &Bs[0][0][0], 0, 0); STG(Bb, &Bs[0][1][0], 0, 1);
    STG(Bb, &Bs[1][0][0], 1, 0); STG(Bb, &Bs[1][1][0], 1, 1);

    for (int i = 0; i < niter - 1; ++i) {
        const int t1 = 2 * i + 1;
        STG(Ab, &As[1][0][0], t1, 0);
        VMC(6); BAR(); SGB0();
        LAF(0, 0); LBF(0, 0); MMQ(0, 0); BAR();
        LBF(0, 1); STG(Ab, &As[1][1][0], t1, 1); BAR(); MMQ(0, 1); BAR();
        LAF(0, 1); STG(Bb, &Bs[0][0][0], t1 + 1, 0); BAR(); MMQ(1, 0); BAR();
        STG(Bb, &Bs[0][1][0], t1 + 1, 1); BAR(); MMQ(1, 1); BAR();
        STG(Ab, &As[0][0][0], t1 + 1, 0);
        VMC(6); BAR(); SGB0();
        LAF(1, 0); LBF(1, 0); MMQ(0, 0); BAR();
        LBF(1, 1); STG(Ab, &As[0][1][0], t1 + 1, 1); BAR(); MMQ(0, 1); BAR();
        LAF(1, 1); STG(Bb, &Bs[1][0][0], t1 + 2, 0); BAR(); MMQ(1, 0); BAR();
        STG(Bb, &Bs[1][1][0], t1 + 2, 1); BAR(); MMQ(1, 1); BAR();
    }
    {   // peeled last iteration
        STG(Ab, &As[1][0][0], nt - 1, 0);
        VMC(6); BAR(); SGB0();
        LAF(0, 0); LBF(0, 0); MMQ(0, 0); BAR();
        LBF(0, 1); STG(Ab, &As[1][1][0], nt - 1, 1); BAR(); MMQ(0, 1); BAR();
        LAF(0, 1); BAR(); MMQ(1, 0); BAR();
        BAR(); MMQ(1, 1); BAR();
        VMC(0); BAR(); SGB0();
        LAF(1, 0); LBF(1, 0); MMQ(0, 0); BAR();
        LBF(1, 1); BAR(); MMQ(0, 1); BAR();
        LAF(1, 1); BAR(); MMQ(1, 0); BAR();
        BAR(); MMQ(1, 1); BAR();
    }
#undef LAF
#undef LBF
#undef MMQ
#undef BAR
#undef VMC
#undef SGB0

#pragma unroll
    for (int mi = 0; mi < 8; ++mi)
#pragma unroll
        for (int ni = 0; ni < 4; ++ni) {
            const int colg = n0 + wc * 64 + ni * 16 + lr;
#pragma unroll
            for (int r = 0; r < 4; ++r) {
                const int rowg = m0 + wr * 128 + mi * 16 + 4 * g + r;
                epi_write<EPI>(outp, res, N, rowg, colg, acc[mi][ni][r]);
            }
        }
}

// ---------------- 2-phase 128xBN dbuf GEMM (split-K capable) ----------------
// EPI 4 (QKV): Q/K written direct; V staged through LDS transpose tile.
// EPI 5: store bf16 partial (part 0 -> outp, part 1 -> res cast).
template <int BM, int BN, int EPI>
__global__ __launch_bounds__(256) void gemm_bf16(
    const __bf16* __restrict__ A, const __bf16* __restrict__ Bt,
    void* __restrict__ outp, const float* __restrict__ res,
    int M, int N, int K, int Kld)
{
    __shared__ __bf16 As[2][BM * 64];
    __shared__ __bf16 Bs[2][BN * 64];
    const int tid = threadIdx.x;

    const int gx = gridDim.x, nwg = gx * gridDim.y;
    int bid = blockIdx.y * gx + blockIdx.x;
    int m0, n0;
    if constexpr (EPI == 4) {
        // gx = 32, gy = 32: 2D regions of 8m x 16n per XCD
        const int xcd = bid & 7, c = bid >> 3;   // c in [0,128)
        const int rm = xcd >> 1, rn = xcd & 1;   // 4 x 2 regions
        m0 = (rm * 8 + (c >> 4)) * BM;
        n0 = (rn * 16 + (c & 15)) * BN;
    } else {
        if ((nwg & 7) == 0) bid = (bid & 7) * (nwg >> 3) + (bid >> 3);
        m0 = (bid / gx) * BM; n0 = (bid % gx) * BN;
    }

    const int lane = tid & 63, w = tid >> 6;
    const int wm = w >> 1, wn = w & 1;
    const int lr = lane & 15, g = lane >> 4;
    const int srow = lane >> 3;
    const int scol = ((lane & 7) ^ srow) * 8;
    const int xr8 = lr & 7;

    constexpr int MI = BM / 32, NI = BN / 32;
    f32x4 acc[MI][NI] = {};

    const __bf16* Abase = A + (size_t)m0 * Kld + blockIdx.z * K;
    const __bf16* Bbase = Bt + (size_t)n0 * Kld + blockIdx.z * K;

    auto STAGE = [&](int kb, int buf) {
#pragma unroll
        for (int j = 0; j < BM / 32; ++j) {
            const int s = j * 4 + w;
            GLDS16(Abase + (size_t)(s * 8 + srow) * Kld + kb + scol, &As[buf][s * 512]);
        }
#pragma unroll
        for (int j = 0; j < BN / 32; ++j) {
            const int s = j * 4 + w;
            GLDS16(Bbase + (size_t)(s * 8 + srow) * Kld + kb + scol, &Bs[buf][s * 512]);
        }
    };

    const int nt = K >> 6;
    STAGE(0, 0);
    __syncthreads();

    for (int t = 0; t < nt; ++t) {
        const int cur = t & 1;
        if (t + 1 < nt) STAGE((t + 1) << 6, cur ^ 1);

        bf16x8 af[2][MI], bfr[2][NI];
#pragma unroll
        for (int kk = 0; kk < 2; ++kk) {
#pragma unroll
            for (int i = 0; i < MI; ++i)
                af[kk][i] = *(const bf16x8*)
                    &As[cur][(wm * (BM / 2) + i * 16 + lr) * 64 + (((kk * 4 + g) ^ xr8) << 3)];
#pragma unroll
            for (int i = 0; i < NI; ++i)
                bfr[kk][i] = *(const bf16x8*)
                    &Bs[cur][(wn * (BN / 2) + i * 16 + lr) * 64 + (((kk * 4 + g) ^ xr8) << 3)];
        }
#pragma unroll
        for (int kk = 0; kk < 2; ++kk)
#pragma unroll
            for (int mi = 0; mi < MI; ++mi)
#pragma unroll
                for (int ni = 0; ni < NI; ++ni)
                    acc[mi][ni] = MFMA_16x16x32_BF16(af[kk][mi], bfr[kk][ni], acc[mi][ni]);
        if (t + 1 < nt) __syncthreads();
    }

    if constexpr (EPI == 4) {
        __bf16* vtile = (__bf16*)As;                 // 32KB >= BN*128*2B
        const bool hasV = (n0 + BN > 2048);
        if (hasV) __syncthreads();                   // As free for reuse
#pragma unroll
        for (int mi = 0; mi < MI; ++mi)
#pragma unroll
            for (int ni = 0; ni < NI; ++ni) {
                const int colg = n0 + wn * (BN / 2) + ni * 16 + lr;
#pragma unroll
                for (int r = 0; r < 4; ++r) {
                    const int rowg = m0 + wm * (BM / 2) + mi * 16 + 4 * g + r;
                    const float v = acc[mi][ni][r];
                    if (colg < 2048) {
                        ((__bf16*)outp)[(size_t)(colg >> 10) * 4194304 +
                                        (size_t)rowg * 1024 + (colg & 1023)] = (__bf16)v;
                    } else {
                        // stage into LDS, pre-permuted: trow 16h+4g'+j -> 8g'+4h+j
                        const int trow = rowg - m0;
                        const int r32 = trow & 31;
                        const int p = ((r32 & 12) << 1) | ((r32 >> 2) & 4) | (r32 & 3);
                        vtile[(colg - n0) * 128 + (trow & ~31) + p] = (__bf16)v;
                    }
                }
            }
        if (hasV) {
            __syncthreads();
            const int vstart = (2048 > n0) ? (2048 - n0) : 0;
            const int nvec = (BN - vstart) * 16;     // bf16x8 vectors
            __bf16* base = (__bf16*)outp;
            const size_t vt0 = 8388608 + (size_t)((m0 >> 11) * 16) * 64 * 2048 +
                               (m0 & 2047);
            for (int v = tid; v < nvec; v += 256) {
                const int vc = vstart + (v >> 4);
                const int t8 = (v & 15) << 3;
                const int cg = (n0 + vc) & 1023;
                const size_t idx = vt0 + ((size_t)(cg >> 6) * 64 + (cg & 63)) * 2048 + t8;
                *(bf16x8*)&base[idx] = *(const bf16x8*)&vtile[vc * 128 + t8];
            }
        }
    } else {
#pragma unroll
        for (int mi = 0; mi < MI; ++mi)
#pragma unroll
            for (int ni = 0; ni < NI; ++ni) {
                const int colg = n0 + wn * (BN / 2) + ni * 16 + lr;
#pragma unroll
                for (int r = 0; r < 4; ++r) {
                    const int rowg = m0 + wm * (BM / 2) + mi * 16 + 4 * g + r;
                    const float v = acc[mi][ni][r];
                    if constexpr (EPI == 5) {
                        __bf16* pout = (blockIdx.z == 0) ? (__bf16*)outp
                                                         : (__bf16*)(void*)res;
                        pout[(size_t)rowg * N + colg] = (__bf16)v;
                    } else {
                        epi_write<EPI>(outp, res, N, rowg, colg, v);
                    }
                }
            }
    }
}

// ---------------- Flash-style causal attention (8-wave, KVBLK=128) ----------
// Grid: 512 blocks = j*32 + bh, j in [0,16). qc = j<8 ? j : 23-j (balanced).
// Block-uniform FULL fast path for t<qc; deferred softmax; row-sum via
// ones-column MFMA (accS, already in D-layout -> no shuffles).
__global__ __launch_bounds__(512) void attn_kernel(
    const __bf16* __restrict__ Q, const __bf16* __restrict__ Kb,
    const __bf16* __restrict__ Vt, __bf16* __restrict__ ctx)
{
    const int Dm = 1024, T = 2048;
    const int tid = threadIdx.x;
    const int w = tid >> 6, lane = tid & 63;
    const int lr = lane & 15, g = lane >> 4;
    const int bx = blockIdx.x;
    const int j = bx >> 5, bh = bx & 31, b = bh >> 4, h = bh & 15;
    const int qc = (j < 8) ? j : 23 - j;            // balanced bijection 0..15
    const int qbase = qc * 128 + w * 16;
    const size_t rowoff = (size_t)b * T;
    const __bf16* Qp = Q + rowoff * Dm + h * 64;
    const __bf16* Kp = Kb + rowoff * Dm + h * 64;
    const __bf16* Vtp = Vt + (size_t)bh * 64 * 2048;

    __shared__ __bf16 Ks[2][128 * 64];
    __shared__ __bf16 Vs[2][64 * 128];

    bf16x8 qf0 = *(const bf16x8*)&Qp[(size_t)(qbase + lr) * Dm + g * 8];
    bf16x8 qf1 = *(const bf16x8*)&Qp[(size_t)(qbase + lr) * Dm + 32 + g * 8];
    const float qsc = 0.125f * 1.44269504088896340736f;
#pragma unroll
    for (int jj = 0; jj < 8; ++jj) {
        qf0[jj] = (__bf16)((float)qf0[jj] * qsc);
        qf1[jj] = (__bf16)((float)qf1[jj] * qsc);
    }
    bf16x8 ones;
#pragma unroll
    for (int jj = 0; jj < 8; ++jj) ones[jj] = (__bf16)1.0f;

    const int ksrow = lane >> 3;
    const int kschunk = (lane & 7) ^ ksrow;
    const int vsrow = lane >> 4;                    // 0..3

    f32x4 acc[4] = {};
    f32x4 accS = {};                                // row-sum accumulator
    float m_s = -__builtin_inff();
    const int nsteps = qc + 1;
    const f32x4 zacc = {0.0f, 0.0f, 0.0f, 0.0f};
    const int x8 = lr & 7;                          // K read chunk XOR
    const int qg = qbase + lr;

    auto STAGE = [&](int kvb, int buf) {
#pragma unroll
        for (int jj = 0; jj < 2; ++jj) {
            const int krow = w * 16 + jj * 8;
            GLDS16(Kp + (size_t)(kvb + krow + ksrow) * Dm + kschunk * 8,
                   &Ks[buf][krow * 64]);
            const int vrow = w * 8 + jj * 4;
            const int vchunk = (lane & 15) ^ ((vrow + vsrow) & 15);
            GLDS16(Vtp + (size_t)(vrow + vsrow) * T + kvb + vchunk * 8,
                   &Vs[buf][vrow * 128]);
        }
    };

    STAGE(0, 0);
    __syncthreads();

    for (int t = 0; t < nsteps; ++t) {
        const int kvb = t * 128, cur = t & 1;
        if (t + 1 < nsteps) STAGE(kvb + 128, cur ^ 1);

        float sv[8][4];
        if (t < qc) {
            // ---- FULL fast path: whole 128-kv tile live, no mask logic ----
#pragma unroll
            for (int s4 = 0; s4 < 8; ++s4) {
                const int row = s4 * 16 + lr;
                const bf16x8 kfa = *(const bf16x8*)&Ks[cur][row * 64 + ((g ^ x8) << 3)];
                const bf16x8 kfb = *(const bf16x8*)&Ks[cur][row * 64 + (((4 + g) ^ x8) << 3)];
                f32x4 st = MFMA_16x16x32_BF16(kfa, qf0, zacc);
                st = MFMA_16x16x32_BF16(kfb, qf1, st);
#pragma unroll
                for (int r = 0; r < 4; ++r) sv[s4][r] = st[r];
            }
        } else {
            // ---- diagonal step: per-subtile guards + causal mask ----
#pragma unroll
            for (int s4 = 0; s4 < 8; ++s4) {
                const int kv0 = kvb + s4 * 16;
                if (kv0 <= qbase + 15) {
                    const int row = s4 * 16 + lr;
                    const bf16x8 kfa = *(const bf16x8*)&Ks[cur][row * 64 + ((g ^ x8) << 3)];
                    const bf16x8 kfb = *(const bf16x8*)&Ks[cur][row * 64 + (((4 + g) ^ x8) << 3)];
                    f32x4 st = MFMA_16x16x32_BF16(kfa, qf0, zacc);
                    st = MFMA_16x16x32_BF16(kfb, qf1, st);
                    const bool domask = (kv0 + 15 > qbase);
#pragma unroll
                    for (int r = 0; r < 4; ++r) {
                        float x = st[r];
                        if (domask && (kv0 + 4 * g + r > qg)) x = -__builtin_inff();
                        sv[s4][r] = x;
                    }
                } else {
#pragma unroll
                    for (int r = 0; r < 4; ++r) sv[s4][r] = -__builtin_inff();
                }
            }
        }

        // ---- deferred online softmax (log2 domain); v_max3 tree ----
        float tml = fmax3(sv[0][0], sv[0][1], sv[0][2]);
        tml = fmax3(tml, sv[0][3], sv[1][0]);
        tml = fmax3(tml, sv[1][1], sv[1][2]);
        tml = fmax3(tml, sv[1][3], sv[2][0]);
        tml = fmax3(tml, sv[2][1], sv[2][2]);
        tml = fmax3(tml, sv[2][3], sv[3][0]);
        tml = fmax3(tml, sv[3][1], sv[3][2]);
        tml = fmax3(tml, sv[3][3], sv[4][0]);
        tml = fmax3(tml, sv[4][1], sv[4][2]);
        tml = fmax3(tml, sv[4][3], sv[5][0]);
        tml = fmax3(tml, sv[5][1], sv[5][2]);
        tml = fmax3(tml, sv[5][3], sv[6][0]);
        tml = fmax3(tml, sv[6][1], sv[6][2]);
        tml = fmax3(tml, sv[6][3], sv[7][0]);
        tml = fmax3(tml, sv[7][1], sv[7][2]);
        tml = fmaxf(tml, sv[7][3]);

        if (!__all(tml - m_s <= 11.5f)) {
            float tm = fmaxf(tml, __shfl_xor(tml, 16));
            tm = fmaxf(tm, __shfl_xor(tm, 32));
            const float m_new = fmaxf(m_s, tm);
            const float corr = exp2f(m_s - m_new);
            float cr[4];
#pragma unroll
            for (int r = 0; r < 4; ++r) cr[r] = __shfl(corr, 4 * g + r);
#pragma unroll
            for (int ct = 0; ct < 4; ++ct) {
                acc[ct][0] *= cr[0]; acc[ct][1] *= cr[1];
                acc[ct][2] *= cr[2]; acc[ct][3] *= cr[3];
            }
            accS[0] *= cr[0]; accS[1] *= cr[1];
            accS[2] *= cr[2]; accS[3] *= cr[3];
            m_s = m_new;
        }

#pragma unroll
        for (int s4 = 0; s4 < 8; ++s4)
#pragma unroll
            for (int r = 0; r < 4; ++r)
                sv[s4][r] = exp2f(sv[s4][r] - m_s);

        // ---- PV + ones-column row-sum ----
        bf16x8 pa[4];
#pragma unroll
        for (int s = 0; s < 4; ++s)
#pragma unroll
            for (int r = 0; r < 4; ++r) {
                pa[s][r] = (__bf16)sv[2 * s][r];
                pa[s][4 + r] = (__bf16)sv[2 * s + 1][r];
            }
        if (t < qc) {
#pragma unroll
            for (int s = 0; s < 4; ++s)
                accS = MFMA_16x16x32_BF16(pa[s], ones, accS);
#pragma unroll
            for (int ct = 0; ct < 4; ++ct) {
                const __bf16* vrow = &Vs[cur][(ct * 16 + lr) * 128];
#pragma unroll
                for (int s = 0; s < 4; ++s) {
                    const bf16x8 vf = *(const bf16x8*)&vrow[(((s * 4 + g) ^ lr) << 3)];
                    acc[ct] = MFMA_16x16x32_BF16(pa[s], vf, acc[ct]);
                }
            }
        } else {
#pragma unroll
            for (int s = 0; s < 4; ++s)
                if (kvb + s * 32 <= qbase + 15)
                    accS = MFMA_16x16x32_BF16(pa[s], ones, accS);
#pragma unroll
            for (int ct = 0; ct < 4; ++ct) {
                const __bf16* vrow = &Vs[cur][(ct * 16 + lr) * 128];
#pragma unroll
                for (int s = 0; s < 4; ++s) {
                    if (kvb + s * 32 <= qbase + 15) {
                        const bf16x8 vf = *(const bf16x8*)&vrow[(((s * 4 + g) ^ lr) << 3)];
                        acc[ct] = MFMA_16x16x32_BF16(pa[s], vf, acc[ct]);
                    }
                }
            }
        }
        __syncthreads();
    }

    // accS[r] is already the row-sum for q-row 4g+r (D-layout) — no shuffles.
    float dn[4];
#pragma unroll
    for (int r = 0; r < 4; ++r) dn[r] = __builtin_amdgcn_rcpf(accS[r]);
#pragma unroll
    for (int ct = 0; ct < 4; ++ct)
#pragma unroll
        for (int r = 0; r < 4; ++r)
            ctx[(rowoff + qbase + 4 * g + r) * Dm + h * 64 + ct * 16 + lr] =
                (__bf16)(acc[ct][r] * dn[r]);
}

// ---------------------------------------------------------------------------
extern "C" void kernel_launch(void* const* d_in, const int* in_sizes, int n_in,
                              void* d_out, int out_size, void* d_ws, size_t ws_size,
                              hipStream_t stream)
{
    (void)in_sizes; (void)n_in; (void)out_size; (void)ws_size;
    const float* z      = (const float*)d_in[0];
    const float* W_Q    = (const float*)d_in[1];
    const float* W_K    = (const float*)d_in[2];
    const float* W_V    = (const float*)d_in[3];
    const float* W_O    = (const float*)d_in[4];
    const float* W_fc   = (const float*)d_in[5];
    const float* W_proj = (const float*)d_in[6];
    const float* g1     = (const float*)d_in[7];
    const float* g2     = (const float*)d_in[8];
    float* out = (float*)d_out;

    char* ws = (char*)d_ws;
    const size_t MB = (size_t)1 << 20;
    __bf16* WtQKV  = (__bf16*)(ws + 0 * MB);   // [3072][1024]
    __bf16* WtO    = (__bf16*)(ws + 6 * MB);
    __bf16* Wtfc   = (__bf16*)(ws + 8 * MB);
    __bf16* Wtproj = (__bf16*)(ws + 16 * MB);
    __bf16* zn     = (__bf16*)(ws + 24 * MB);  // reused as ctx
    __bf16* Qb     = (__bf16*)(ws + 32 * MB);  // QKV out base; reused as h
    __bf16* Kbuf   = (__bf16*)(ws + 40 * MB);
    __bf16* Vtb    = (__bf16*)(ws + 48 * MB);
    __bf16* ffn1   = (__bf16*)(ws + 40 * MB);  // overlaps K,Vt (dead post-attn)
    __bf16* part0  = (__bf16*)(ws + 0 * MB);   // 8MB bf16: dead WtQKV/WtO
    __bf16* part1  = (__bf16*)(ws + 24 * MB);  // 8MB bf16: dead zn/ctx
    __bf16* ctx    = zn;
    __bf16* hb     = Qb;

    const int Tt = 2048, Dm = 1024, Bb = 2, M = Bb * Tt, DFF = 4096;
    const dim3 blk256(256), blk512(512);

    // fused: weight transposes + rmsnorm(z, g1) -> zn
    fused_head_kernel<<<16384, blk256, 0, stream>>>(
        W_Q, W_K, W_V, W_O, W_fc, W_proj, WtQKV, WtO, Wtfc, Wtproj, z, g1, zn);

    // Fused QKV (2-phase 128x96, 1024 blocks, LDS-transposed V epilogue)
    gemm_bf16<128, 96, 4><<<dim3(32, 32), blk256, 0, stream>>>(
        zn, WtQKV, Qb, nullptr, M, 3072, Dm, Dm);

    // attention -> ctx (8-wave, KVBLK=128, ones-column row-sum)
    attn_kernel<<<512, blk512, 0, stream>>>(Qb, Kbuf, Vtb, ctx);

    // z2 = z + ctx @ W_O  -> d_out (fp32)
    gemm_bf16<128, 64, 1><<<dim3(16, 32), blk256, 0, stream>>>(
        ctx, WtO, out, z, M, Dm, Dm, Dm);

    // h = rmsnorm(z2, g2)
    rmsnorm_kernel<<<M, blk256, 0, stream>>>(out, g2, hb);

    // ffn1 = gelu(h @ W_fc) (8-phase 256^2, 2D XCD regions)
    gemm256<2><<<dim3(16, 16), blk512, 0, stream>>>(
        hb, Wtfc, ffn1, nullptr, M, DFF, Dm);

    // proj split-K=2 (128x128, 512 blocks): bf16 partials p0/p1
    gemm_bf16<128, 128, 5><<<dim3(8, 32, 2), blk256, 0, stream>>>(
        ffn1, Wtproj, part0, (const float*)part1, M, Dm, DFF / 2, DFF);

    // d_out += p0 + p1  (bf16 partials, 8 elems/thread)
    reduce_add_kernel<<<2048, blk256, 0, stream>>>(out, part0, part1, M * Dm / 8);
}